// Round 5
// baseline (99.178 us; speedup 1.0000x reference)
//
#include <hip/hip_runtime.h>

typedef __bf16 bf16x8 __attribute__((ext_vector_type(8)));
typedef float  f32x4  __attribute__((ext_vector_type(4)));

constexpr int HID = 64;
constexpr float K1   = 27.178297f;        // sqrt(512*log2 e); enc = exp2(-(K1*(x-c))^2)
constexpr float STEP = -K1 / 31.0f;       // centers[i] = i/31
// recurrence: u_j = 2^{-d_j^2}, d_j = a + j*STEP
//   u_{j+1} = u_j * v_j,  v_j = 2^{-(2 a STEP + (2j+1) STEP^2)},  v_{j+1} = v_j * WMUL
constexpr float M2STEP = -2.0f * STEP;            //  1.7534386
constexpr float NSTEP2 = -STEP * STEP;            // -0.76863675
constexpr float WMUL   = 0.34453753f;             //  2^{-2*STEP^2}

// MFMA 16x16x32 bf16 layouts (verified m89/m91):
//   A-frag: lane l holds A[m=l&15][k=(l>>4)*8+j]
//   B-frag: lane l holds B[k=(l>>4)*8+j][n=l&15]
//   C/D  : lane l reg i holds D[m=(l>>4)*4+i][n=l&15]
// Transposed compute: D[c][row] = W^T @ enc^T. k-permutation
// pi(32kk2+8g+j) = 32kk2+16(j>>2)+4g+(j&3) on W2/W3 rows makes each layer's
// B-frag equal to the previous layer's accumulators repacked in-lane.

// ws layout (bf16x8 units): frag f in [0,28): W1 [kk*4+mt];
// f in [28,36): W2 [mt*2+kk2]; f in [36,44): W3 [mt*2+kk2]. 64 lanes each.
__global__ void prep_kernel(const float* __restrict__ W1,
                            const float* __restrict__ W2,
                            const float* __restrict__ W3,
                            bf16x8* __restrict__ ws)
{
    const int f = blockIdx.x;
    const int l = threadIdx.x;
    const int g = l >> 4, r = l & 15;
    bf16x8 v;
    if (f < 28) {
        const int kk = f >> 2, mt = f & 3;
#pragma unroll
        for (int j = 0; j < 8; ++j)
            v[j] = (__bf16)W1[(32 * kk + 8 * g + j) * HID + 16 * mt + r];
    } else {
        const float* W = (f < 36) ? W2 : W3;
        const int fi = (f < 36) ? (f - 28) : (f - 36);
        const int mt = fi >> 1, kk2 = fi & 1;
#pragma unroll
        for (int j = 0; j < 8; ++j) {
            const int k = 32 * kk2 + 16 * (j >> 2) + 4 * g + (j & 3);
            v[j] = (__bf16)W[k * HID + 16 * mt + r];
        }
    }
    ws[f * 64 + l] = v;
}

__device__ __forceinline__ void load_x(const float* __restrict__ pos,
                                       const float* __restrict__ wi,
                                       const float* __restrict__ rough,
                                       int row, float* x)
{
    x[0] = pos[row * 3 + 0]; x[1] = pos[row * 3 + 1]; x[2] = pos[row * 3 + 2];
    x[3] = wi[row * 3 + 0];  x[4] = wi[row * 3 + 1];  x[5] = wi[row * 3 + 2];
    x[6] = rough[row];
}

// gen 8 gaussian bins from window start exponent-offset a (d_0 = a)
__device__ __forceinline__ bf16x8 enc8(float a)
{
    bf16x8 e;
    float u = __builtin_amdgcn_exp2f(-(a * a));
    float v = __builtin_amdgcn_exp2f(fmaf(a, M2STEP, NSTEP2));
    e[0] = (__bf16)u;
#pragma unroll
    for (int j = 1; j < 8; ++j) {
        u *= v;
        v *= WMUL;
        e[j] = (__bf16)u;
    }
    return e;
}

// 512 threads = 8 waves; each wave does 32 rows/iter, 8 iters -> 2048 rows/block
__global__ __launch_bounds__(512, 4)
void cond_net_kernel(const float* __restrict__ pos, const float* __restrict__ wi,
                     const float* __restrict__ rough,
                     const float* __restrict__ b1, const float* __restrict__ b2,
                     const float* __restrict__ b3,
                     const bf16x8* __restrict__ ws,
                     float* __restrict__ out)
{
    __shared__ __align__(16) char lds[44 * 1024];   // all weight frags, lane-linear

    const int tid = threadIdx.x;
    const int l = tid & 63, wv = tid >> 6, g = l >> 4, r = l & 15;

    // stage all 44 weight fragments (1 KiB each) via async global->LDS
    for (int fr = wv; fr < 44; fr += 8)
        __builtin_amdgcn_global_load_lds(
            (const __attribute__((address_space(1))) void*)(ws + fr * 64 + l),
            (__attribute__((address_space(3))) void*)(lds + fr * 1024),
            16, 0, 0);

    f32x4 b1v[4], b2v[4], b3v[4];
#pragma unroll
    for (int mt = 0; mt < 4; ++mt) {
        b1v[mt] = *(const f32x4*)(b1 + 16 * mt + 4 * g);
        b2v[mt] = *(const f32x4*)(b2 + 16 * mt + 4 * g);
        b3v[mt] = *(const f32x4*)(b3 + 16 * mt + 4 * g);
    }

    const float base_g = STEP * (float)(8 * g);
    const int rbase = blockIdx.x * 2048 + wv * 32 + r;

    float xc[14];
    load_x(pos, wi, rough, rbase, xc);
    load_x(pos, wi, rough, rbase + 16, xc + 7);

    __syncthreads();   // drains global_load_lds + barrier

    unsigned int ldsoff = 0;
#pragma unroll 1
    for (int it = 0; it < 8; ++it) {
        asm volatile("" : "+v"(ldsoff));          // defeat LICM on LDS reads
        const char* lb = (const char*)lds + ldsoff + l * 16;

        // prefetch next iteration's inputs (consumed at the rotate below)
        float xn[14];
        const int nrow = rbase + ((it + 1) & 7) * 256;
        load_x(pos, wi, rough, nrow, xn);
        load_x(pos, wi, rough, nrow + 16, xn + 7);

        float Aa[7], Ab[7];
#pragma unroll
        for (int d = 0; d < 7; ++d) {
            Aa[d] = fmaf(K1, fminf(fmaxf(xc[d], 0.0f), 1.0f), base_g);
            Ab[d] = fmaf(K1, fminf(fmaxf(xc[7 + d], 0.0f), 1.0f), base_g);
        }

        // ---- layer 1 ----
        f32x4 accA[4], accB[4];
#pragma unroll
        for (int mt = 0; mt < 4; ++mt) { accA[mt] = b1v[mt]; accB[mt] = b1v[mt]; }

#pragma unroll
        for (int kk = 0; kk < 7; ++kk) {
            const bf16x8 e0 = enc8(Aa[kk]);
            const bf16x8 e1 = enc8(Ab[kk]);
#pragma unroll
            for (int mt = 0; mt < 4; ++mt) {
                const bf16x8 wf = *(const bf16x8*)(lb + (kk * 4 + mt) * 1024);
                accA[mt] = __builtin_amdgcn_mfma_f32_16x16x32_bf16(wf, e0, accA[mt], 0, 0, 0);
                accB[mt] = __builtin_amdgcn_mfma_f32_16x16x32_bf16(wf, e1, accB[mt], 0, 0, 0);
            }
        }

        // ---- layers 2+3, both tiles sharing each fragment read ----
        bf16x8 h1fA[2], h1fB[2];
#pragma unroll
        for (int kk2 = 0; kk2 < 2; ++kk2) {
            bf16x8 va, vb;
#pragma unroll
            for (int j = 0; j < 8; ++j) {
                va[j] = (__bf16)fmaxf(accA[2 * kk2 + (j >> 2)][j & 3], 0.0f);
                vb[j] = (__bf16)fmaxf(accB[2 * kk2 + (j >> 2)][j & 3], 0.0f);
            }
            h1fA[kk2] = va; h1fB[kk2] = vb;
        }

        f32x4 acc2A[4], acc2B[4];
#pragma unroll
        for (int mt = 0; mt < 4; ++mt) { acc2A[mt] = b2v[mt]; acc2B[mt] = b2v[mt]; }
#pragma unroll
        for (int kk2 = 0; kk2 < 2; ++kk2)
#pragma unroll
            for (int mt = 0; mt < 4; ++mt) {
                const bf16x8 wf = *(const bf16x8*)(lb + (28 + mt * 2 + kk2) * 1024);
                acc2A[mt] = __builtin_amdgcn_mfma_f32_16x16x32_bf16(wf, h1fA[kk2], acc2A[mt], 0, 0, 0);
                acc2B[mt] = __builtin_amdgcn_mfma_f32_16x16x32_bf16(wf, h1fB[kk2], acc2B[mt], 0, 0, 0);
            }

        bf16x8 h2fA[2], h2fB[2];
#pragma unroll
        for (int kk2 = 0; kk2 < 2; ++kk2) {
            bf16x8 va, vb;
#pragma unroll
            for (int j = 0; j < 8; ++j) {
                va[j] = (__bf16)fmaxf(acc2A[2 * kk2 + (j >> 2)][j & 3], 0.0f);
                vb[j] = (__bf16)fmaxf(acc2B[2 * kk2 + (j >> 2)][j & 3], 0.0f);
            }
            h2fA[kk2] = va; h2fB[kk2] = vb;
        }

        f32x4 acc3A[4], acc3B[4];
#pragma unroll
        for (int mt = 0; mt < 4; ++mt) { acc3A[mt] = b3v[mt]; acc3B[mt] = b3v[mt]; }
#pragma unroll
        for (int kk2 = 0; kk2 < 2; ++kk2)
#pragma unroll
            for (int mt = 0; mt < 4; ++mt) {
                const bf16x8 wf = *(const bf16x8*)(lb + (36 + mt * 2 + kk2) * 1024);
                acc3A[mt] = __builtin_amdgcn_mfma_f32_16x16x32_bf16(wf, h2fA[kk2], acc3A[mt], 0, 0, 0);
                acc3B[mt] = __builtin_amdgcn_mfma_f32_16x16x32_bf16(wf, h2fB[kk2], acc3B[mt], 0, 0, 0);
            }

        const int row0 = rbase + it * 256;
#pragma unroll
        for (int mt = 0; mt < 4; ++mt) {
            __builtin_nontemporal_store(acc3A[mt],
                (f32x4*)(out + (size_t)row0 * 64 + 16 * mt + 4 * g));
            __builtin_nontemporal_store(acc3B[mt],
                (f32x4*)(out + (size_t)(row0 + 16) * 64 + 16 * mt + 4 * g));
        }

#pragma unroll
        for (int q = 0; q < 14; ++q) xc[q] = xn[q];
    }
}

extern "C" void kernel_launch(void* const* d_in, const int* in_sizes, int n_in,
                              void* d_out, int out_size, void* d_ws, size_t ws_size,
                              hipStream_t stream) {
    const float* pos     = (const float*)d_in[0];
    const float* wi      = (const float*)d_in[1];
    const float* rough   = (const float*)d_in[2];
    const float* W1      = (const float*)d_in[3];
    const float* b1      = (const float*)d_in[4];
    const float* W2      = (const float*)d_in[5];
    const float* b2      = (const float*)d_in[6];
    const float* W3      = (const float*)d_in[7];
    const float* b3      = (const float*)d_in[8];
    float* out = (float*)d_out;

    bf16x8* ws = (bf16x8*)d_ws;

    const int n = in_sizes[0] / 3;          // 1048576 rows
    hipLaunchKernelGGL(prep_kernel, dim3(44), dim3(64), 0, stream, W1, W2, W3, ws);
    hipLaunchKernelGGL(cond_net_kernel, dim3(n / 2048), dim3(512), 0, stream,
                       pos, wi, rough, b1, b2, b3, (const bf16x8*)ws, out);
}

// Round 6
// 92.365 us; speedup vs baseline: 1.0738x; 1.0738x over previous
//
#include <hip/hip_runtime.h>

typedef __bf16 bf16x8 __attribute__((ext_vector_type(8)));
typedef float  f32x4  __attribute__((ext_vector_type(4)));

constexpr int HID = 64;
constexpr float K1   = 27.178297f;        // sqrt(512*log2 e); enc = exp2(-(K1*(x-c))^2)
constexpr float STEP = -K1 / 31.0f;       // centers[i] = i/31
// recurrence: u_j = 2^{-d_j^2}, d_j = a + j*STEP
//   u_{j+1} = u_j * v_j,  v_j = 2^{-(2aS+(2j+1)S^2)} = v_0 * WMUL^j
constexpr float M2STEP = -2.0f * STEP;            //  1.7534386
constexpr float NSTEP2 = -STEP * STEP;            // -0.76863675
constexpr float WMUL   = 0.34453753f;             //  2^{-2*STEP^2}

// MFMA 16x16x32 bf16 layouts (verified m89/m91):
//   A-frag: lane l holds A[m=l&15][k=(l>>4)*8+j]
//   B-frag: lane l holds B[k=(l>>4)*8+j][n=l&15]
//   C/D  : lane l reg i holds D[m=(l>>4)*4+i][n=l&15]
// Transposed compute: D[c][row] = W^T @ enc^T. k-permutation
// pi(32kk2+8g+j) = 32kk2+16(j>>2)+4g+(j&3) on W2/W3 rows makes each layer's
// B-frag equal to the previous layer's accumulators repacked in-lane.

// ws layout (bf16x8 units): frag f in [0,28): W1 [kk*4+mt];
// f in [28,36): W2 [mt*2+kk2]; f in [36,44): W3 [mt*2+kk2]. 64 lanes each.
__global__ void prep_kernel(const float* __restrict__ W1,
                            const float* __restrict__ W2,
                            const float* __restrict__ W3,
                            bf16x8* __restrict__ ws)
{
    const int f = blockIdx.x;
    const int l = threadIdx.x;
    const int g = l >> 4, r = l & 15;
    bf16x8 v;
    if (f < 28) {
        const int kk = f >> 2, mt = f & 3;
#pragma unroll
        for (int j = 0; j < 8; ++j)
            v[j] = (__bf16)W1[(32 * kk + 8 * g + j) * HID + 16 * mt + r];
    } else {
        const float* W = (f < 36) ? W2 : W3;
        const int fi = (f < 36) ? (f - 28) : (f - 36);
        const int mt = fi >> 1, kk2 = fi & 1;
#pragma unroll
        for (int j = 0; j < 8; ++j) {
            const int k = 32 * kk2 + 16 * (j >> 2) + 4 * g + (j & 3);
            v[j] = (__bf16)W[k * HID + 16 * mt + r];
        }
    }
    ws[f * 64 + l] = v;
}

__device__ __forceinline__ void load_x(const float* __restrict__ pos,
                                       const float* __restrict__ wi,
                                       const float* __restrict__ rough,
                                       int row, float* x)
{
    x[0] = pos[row * 3 + 0]; x[1] = pos[row * 3 + 1]; x[2] = pos[row * 3 + 2];
    x[3] = wi[row * 3 + 0];  x[4] = wi[row * 3 + 1];  x[5] = wi[row * 3 + 2];
    x[6] = rough[row];
}

// 8 gaussian bins from window-start offset a (d_0 = a), multiplicative recurrence
__device__ __forceinline__ bf16x8 enc8(float a)
{
    bf16x8 e;
    float u = __builtin_amdgcn_exp2f(-(a * a));
    float v = __builtin_amdgcn_exp2f(fmaf(a, M2STEP, NSTEP2));
    e[0] = (__bf16)u;
#pragma unroll
    for (int j = 1; j < 8; ++j) {
        u *= v;
        v *= WMUL;
        e[j] = (__bf16)u;
    }
    return e;
}

__device__ __forceinline__ void mlp_tail(const f32x4* acc1, const char* lb,
                                         const char* bb,
                                         float* __restrict__ out, int row, int g)
{
    bf16x8 h1f[2];
#pragma unroll
    for (int kk2 = 0; kk2 < 2; ++kk2) {
        bf16x8 v;
#pragma unroll
        for (int j = 0; j < 8; ++j)
            v[j] = (__bf16)fmaxf(acc1[2 * kk2 + (j >> 2)][j & 3], 0.0f);
        h1f[kk2] = v;
    }
    f32x4 acc2[4];
#pragma unroll
    for (int mt = 0; mt < 4; ++mt) acc2[mt] = *(const f32x4*)(bb + 256 + mt * 64);
#pragma unroll
    for (int kk2 = 0; kk2 < 2; ++kk2)
#pragma unroll
        for (int mt = 0; mt < 4; ++mt) {
            const bf16x8 wf = *(const bf16x8*)(lb + (28 + mt * 2 + kk2) * 1024);
            acc2[mt] = __builtin_amdgcn_mfma_f32_16x16x32_bf16(wf, h1f[kk2], acc2[mt], 0, 0, 0);
        }

    bf16x8 h2f[2];
#pragma unroll
    for (int kk2 = 0; kk2 < 2; ++kk2) {
        bf16x8 v;
#pragma unroll
        for (int j = 0; j < 8; ++j)
            v[j] = (__bf16)fmaxf(acc2[2 * kk2 + (j >> 2)][j & 3], 0.0f);
        h2f[kk2] = v;
    }
    f32x4 acc3[4];
#pragma unroll
    for (int mt = 0; mt < 4; ++mt) acc3[mt] = *(const f32x4*)(bb + 512 + mt * 64);
#pragma unroll
    for (int kk2 = 0; kk2 < 2; ++kk2)
#pragma unroll
        for (int mt = 0; mt < 4; ++mt) {
            const bf16x8 wf = *(const bf16x8*)(lb + (36 + mt * 2 + kk2) * 1024);
            acc3[mt] = __builtin_amdgcn_mfma_f32_16x16x32_bf16(wf, h2f[kk2], acc3[mt], 0, 0, 0);
        }
#pragma unroll
    for (int mt = 0; mt < 4; ++mt)
        __builtin_nontemporal_store(acc3[mt],
            (f32x4*)(out + (size_t)row * 64 + 16 * mt + 4 * g));
}

__global__ __launch_bounds__(512, 4)
void cond_net_kernel(const float* __restrict__ pos, const float* __restrict__ wi,
                     const float* __restrict__ rough,
                     const float* __restrict__ b1, const float* __restrict__ b2,
                     const float* __restrict__ b3,
                     const bf16x8* __restrict__ ws,
                     float* __restrict__ out)
{
    __shared__ __align__(16) char lds[44 * 1024 + 768];   // weight frags + biases

    const int tid = threadIdx.x;
    const int l = tid & 63, wv = tid >> 6, g = l >> 4, r = l & 15;

    // stage all 44 weight fragments via async global->LDS, lane-linear
    for (int fr = wv; fr < 44; fr += 8)
        __builtin_amdgcn_global_load_lds(
            (const __attribute__((address_space(1))) void*)(ws + fr * 64 + l),
            (__attribute__((address_space(3))) void*)(lds + fr * 1024),
            16, 0, 0);
    // stage biases (64 f32 each) at 44 KiB, one wave each
    if (wv < 3) {
        const float* bp = (wv == 0) ? b1 : (wv == 1) ? b2 : b3;
        __builtin_amdgcn_global_load_lds(
            (const __attribute__((address_space(1))) void*)(bp + l),
            (__attribute__((address_space(3))) void*)(lds + 44 * 1024 + wv * 256),
            4, 0, 0);
    }

    const float base_g = STEP * (float)(8 * g);
    const int rbase = blockIdx.x * 1024 + wv * 32 + r;

    // iter-0 inputs, in-register
    float xc[14];
    load_x(pos, wi, rough, rbase, xc);
    load_x(pos, wi, rough, rbase + 16, xc + 7);

    __syncthreads();   // drains global_load_lds + barrier

    unsigned int ldsoff = 0;
#pragma unroll 1
    for (int it = 0; it < 4; ++it) {
        asm volatile("" : "+v"(ldsoff));          // defeat LICM on LDS reads
        const char* lb = (const char*)lds + ldsoff + l * 16;
        const char* bb = (const char*)lds + ldsoff + 44 * 1024 + g * 16;

        // prefetch next iteration's inputs (awaited only at the rotate below)
        float xn[14];
        const int nrow = rbase + (it < 3 ? (it + 1) * 256 : 768);
        load_x(pos, wi, rough, nrow, xn);
        load_x(pos, wi, rough, nrow + 16, xn + 7);

        float Aa[7], Ab[7];
#pragma unroll
        for (int d = 0; d < 7; ++d) {
            Aa[d] = fmaf(K1, fminf(fmaxf(xc[d], 0.0f), 1.0f), base_g);
            Ab[d] = fmaf(K1, fminf(fmaxf(xc[7 + d], 0.0f), 1.0f), base_g);
        }

        f32x4 accA[4], accB[4];
#pragma unroll
        for (int mt = 0; mt < 4; ++mt) {
            const f32x4 bv = *(const f32x4*)(bb + mt * 64);
            accA[mt] = bv; accB[mt] = bv;
        }

#pragma unroll
        for (int kk = 0; kk < 7; ++kk) {
            const bf16x8 e0 = enc8(Aa[kk]);
            const bf16x8 e1 = enc8(Ab[kk]);
#pragma unroll
            for (int mt = 0; mt < 4; ++mt) {
                const bf16x8 wf = *(const bf16x8*)(lb + (kk * 4 + mt) * 1024);
                accA[mt] = __builtin_amdgcn_mfma_f32_16x16x32_bf16(wf, e0, accA[mt], 0, 0, 0);
                accB[mt] = __builtin_amdgcn_mfma_f32_16x16x32_bf16(wf, e1, accB[mt], 0, 0, 0);
            }
        }

        const int row0 = rbase + it * 256;
        mlp_tail(accA, lb, bb, out, row0, g);
        mlp_tail(accB, lb, bb, out, row0 + 16, g);

#pragma unroll
        for (int q = 0; q < 14; ++q) xc[q] = xn[q];
    }
}

extern "C" void kernel_launch(void* const* d_in, const int* in_sizes, int n_in,
                              void* d_out, int out_size, void* d_ws, size_t ws_size,
                              hipStream_t stream) {
    const float* pos     = (const float*)d_in[0];
    const float* wi      = (const float*)d_in[1];
    const float* rough   = (const float*)d_in[2];
    const float* W1      = (const float*)d_in[3];
    const float* b1      = (const float*)d_in[4];
    const float* W2      = (const float*)d_in[5];
    const float* b2      = (const float*)d_in[6];
    const float* W3      = (const float*)d_in[7];
    const float* b3      = (const float*)d_in[8];
    float* out = (float*)d_out;

    bf16x8* ws = (bf16x8*)d_ws;

    const int n = in_sizes[0] / 3;          // 1048576 rows
    hipLaunchKernelGGL(prep_kernel, dim3(44), dim3(64), 0, stream, W1, W2, W3, ws);
    hipLaunchKernelGGL(cond_net_kernel, dim3(n / 1024), dim3(512), 0, stream,
                       pos, wi, rough, b1, b2, b3, (const bf16x8*)ws, out);
}